// Round 12
// baseline (181.791 us; speedup 1.0000x reference)
//
#include <hip/hip_runtime.h>
#include <hip/hip_bf16.h>
#include <math.h>

#define BQn 2
#define QN 13294
#define SN 13294
#define NH 8
#define DH 32
#define DM 256

typedef __attribute__((ext_vector_type(8))) short short8;
typedef __attribute__((ext_vector_type(4))) float f32x4;

__device__ __forceinline__ unsigned short f2bf(float x) {
    union { float f; unsigned int u; } c; c.f = x;
    unsigned int r = c.u + 0x7fff + ((c.u >> 16) & 1);   // RNE
    return (unsigned short)(r >> 16);
}
__device__ __forceinline__ float asf(unsigned int u) {
    union { unsigned int i; float f; } c; c.i = u; return c.f;
}

// ---------------------------------------------------------------------------
// Fused transpose+bf16 of all four weight matrices: W[K][N] -> WT[N][K]
// WoffT/WaT adjacent -> WcatT[384][256] for the merged off+attn GEMM.
// ---------------------------------------------------------------------------
__global__ __launch_bounds__(256) void conv_weights(
    const float* __restrict__ Wv, const float* __restrict__ Woff,
    const float* __restrict__ Wa, const float* __restrict__ Wout,
    unsigned short* __restrict__ WvT, unsigned short* __restrict__ WoffT,
    unsigned short* __restrict__ WaT, unsigned short* __restrict__ WoutT)
{
    const int t = blockIdx.x * 256 + threadIdx.x;
    if (t < 65536) {
        const int n = t & 255, k = t >> 8;
        WvT[(size_t)n * 256 + k] = f2bf(Wv[(size_t)k * 256 + n]);
    } else if (t < 131072) {
        const int i = t - 65536, n = i & 255, k = i >> 8;
        WoffT[(size_t)n * 256 + k] = f2bf(Woff[(size_t)k * 256 + n]);
    } else if (t < 163840) {
        const int i = t - 131072, n = i & 127, k = i >> 7;
        WaT[(size_t)n * 256 + k] = f2bf(Wa[(size_t)k * 128 + n]);
    } else if (t < 229376) {
        const int i = t - 163840, n = i & 255, k = i >> 8;
        WoutT[(size_t)n * 256 + k] = f2bf(Wout[(size_t)k * 256 + n]);
    }
}

// ---------------------------------------------------------------------------
// bf16 MFMA GEMM: C[M,N] = A[M,256] @ WT[N,256]^T + bias
// 64x128 tile, BK=128 (2 K-steps), 4 waves (2x2), wave = 32x64 (2x4 frags).
// Software-pipelined: step-1 global loads issue BEFORE step-0's MFMA so the
// HBM/L2 latency hides under the 32-MFMA burst; __syncthreads only.
// AF32: A fp32 -> bf16 in staging (v_cvt_pk_bf16_f32). Bias split at col 256.
// MODE 0: f32 row-major; MODE 1: bf16 value layout C[b][h][s][dh].
// ---------------------------------------------------------------------------
template<int N, int MODE, bool AF32>
__global__ __launch_bounds__(256) void gemm_mfma(
    const void* __restrict__ Av,            // [M][256] fp32 or bf16
    const unsigned short* __restrict__ WT,  // [N][256] bf16
    const float* __restrict__ bias0,        // [min(N,256)] fp32
    const float* __restrict__ bias1,        // [N-256] fp32 (if N>256)
    void* __restrict__ Cv, int M)
{
    __shared__ unsigned short As[64][136];   // +8 pad: ~2-way alias only
    __shared__ unsigned short Bs[128][136];
    const int tid  = threadIdx.x;
    const int lane = tid & 63, wid = tid >> 6;
    const int wr = wid >> 1, wc = wid & 1;
    const int r0 = blockIdx.y * 64, n0 = blockIdx.x * 128;

    // staging registers (static indices only; loops fully unrolled)
    float4 paf[4][2];   // AF32 A slots
    uint4  pa[4];       // bf16 A slots
    uint4  pb[8];       // B slots

    auto LOADA = [&](int k0) {
        #pragma unroll
        for (int i = 0; i < 4; ++i) {        // A tile 64x128
            const int idx = i * 256 + tid;
            const int row = idx >> 4, ch = (idx & 15) << 3;
            int grow = r0 + row; if (grow >= M) grow = M - 1;
            if (AF32) {
                const float* Af = (const float*)Av;
                paf[i][0] = *(const float4*)(Af + (size_t)grow * 256 + k0 + ch);
                paf[i][1] = *(const float4*)(Af + (size_t)grow * 256 + k0 + ch + 4);
            } else {
                pa[i] = *(const uint4*)((const unsigned short*)Av
                                        + (size_t)grow * 256 + k0 + ch);
            }
        }
    };
    auto LOADB = [&](int k0) {
        #pragma unroll
        for (int i = 0; i < 8; ++i) {        // B tile 128x128 (rows = N cols)
            const int idx = i * 256 + tid;
            const int row = idx >> 4, ch = (idx & 15) << 3;
            pb[i] = *(const uint4*)(WT + (size_t)(n0 + row) * 256 + k0 + ch);
        }
    };
    auto STORE = [&]() {
        #pragma unroll
        for (int i = 0; i < 4; ++i) {
            const int idx = i * 256 + tid;
            const int row = idx >> 4, ch = (idx & 15) << 3;
            if (AF32) {
                union { __hip_bfloat162 b[4]; uint4 u; } pk;
                pk.b[0] = __float22bfloat162_rn(make_float2(paf[i][0].x, paf[i][0].y));
                pk.b[1] = __float22bfloat162_rn(make_float2(paf[i][0].z, paf[i][0].w));
                pk.b[2] = __float22bfloat162_rn(make_float2(paf[i][1].x, paf[i][1].y));
                pk.b[3] = __float22bfloat162_rn(make_float2(paf[i][1].z, paf[i][1].w));
                *(uint4*)&As[row][ch] = pk.u;
            } else {
                *(uint4*)&As[row][ch] = pa[i];
            }
        }
        #pragma unroll
        for (int i = 0; i < 8; ++i) {
            const int idx = i * 256 + tid;
            const int row = idx >> 4, ch = (idx & 15) << 3;
            *(uint4*)&Bs[row][ch] = pb[i];
        }
    };

    f32x4 acc[2][4] = {};

    auto MFMA_STEP = [&]() {
        #pragma unroll
        for (int kk = 0; kk < 4; ++kk) {
            const int kb = kk * 32 + (lane >> 4) * 8;
            short8 bfr[4];
            #pragma unroll
            for (int n = 0; n < 4; ++n)
                bfr[n] = *(const short8*)&Bs[wc * 64 + n * 16 + (lane & 15)][kb];
            #pragma unroll
            for (int m = 0; m < 2; ++m) {
                const short8 afr =
                    *(const short8*)&As[wr * 32 + m * 16 + (lane & 15)][kb];
                #pragma unroll
                for (int n = 0; n < 4; ++n)
                    acc[m][n] = __builtin_amdgcn_mfma_f32_16x16x32_bf16(
                        afr, bfr[n], acc[m][n], 0, 0, 0);
            }
        }
    };

    // pipelined 2-step K loop
    LOADA(0);  LOADB(0);
    STORE();
    __syncthreads();
    LOADA(128); LOADB(128);     // prefetch: flies under step-0 MFMA
    MFMA_STEP();
    __syncthreads();            // drain (residual wait only)
    STORE();
    __syncthreads();
    MFMA_STEP();

    #pragma unroll
    for (int m = 0; m < 2; ++m)
        #pragma unroll
        for (int n = 0; n < 4; ++n) {
            const int col = n0 + wc * 64 + n * 16 + (lane & 15);
            const float bsv = (col < 256) ? bias0[col] : bias1[col - 256];
            #pragma unroll
            for (int j = 0; j < 4; ++j) {
                const int row = r0 + wr * 32 + m * 16 + (lane >> 4) * 4 + j;
                if (row >= M) continue;
                const float v = acc[m][n][j] + bsv;
                if (MODE == 0) {
                    ((float*)Cv)[(size_t)row * N + col] = v;
                } else {
                    const int b = (row >= SN), s = row - b * SN;
                    const int h = col >> 5, dh = col & 31;
                    ((unsigned short*)Cv)
                        [(((size_t)b * NH + h) * SN + s) * DH + dh] = f2bf(v);
                }
            }
        }
}

// ---------------------------------------------------------------------------
// Deformable sampling v5 (owner-compute; proven: 67 us, VGPR 36):
// block = (head, 32-query chunk); h = blockIdx.x & 7 pins each head's two
// bf16 value planes in one XCD's L2. 8 lanes per (b,q,h); lane lc owns
// channels [4lc,4lc+4) AND point-pairs 2lc,2lc+1. Owner precomputes clamped
// rows/cols + validity-and-attention-folded bilinear weights; group
// shfl-broadcasts 8 results per point.
// ---------------------------------------------------------------------------
__global__ __launch_bounds__(256) void ms_sample(
    const unsigned short* __restrict__ value, // [B,H,S,32] bf16
    const float* __restrict__ offaw,          // [B*Q,384] (256 off | 128 logits)
    const float* __restrict__ refp,           // [B,Q,4,2]
    unsigned short* __restrict__ outh,        // [B,Q,256] bf16
    float* __restrict__ awout)                // [B,Q,128]
{
    const int h  = blockIdx.x & 7;
    const int qc = blockIdx.x >> 3;
    const int lc = threadIdx.x & 7;
    const int bq = qc * 32 + (threadIdx.x >> 3);
    if (bq >= BQn * QN) return;
    const int b  = (bq >= QN);
    const int gbase = threadIdx.x & 56;

    const float* rowp = offaw + (size_t)bq * 384;

    // distributed softmax over 16 logits: 2 per lane
    const float2 lw2 = *(const float2*)(rowp + 256 + h * 16 + lc * 2);
    float m = fmaxf(lw2.x, lw2.y);
    #pragma unroll
    for (int d = 1; d < 8; d <<= 1) m = fmaxf(m, __shfl_xor(m, d, 8));
    float e0 = __expf(lw2.x - m), e1 = __expf(lw2.y - m);
    float s = e0 + e1;
    #pragma unroll
    for (int d = 1; d < 8; d <<= 1) s += __shfl_xor(s, d, 8);
    const float inv = 1.f / s;
    e0 *= inv; e1 *= inv;
    *(float2*)(awout + (size_t)bq * 128 + h * 16 + lc * 2) = make_float2(e0, e1);

    // ---- owner precompute: this lane's level constants + its two points ----
    const int lvl = lc >> 1;
    const int wi  = (lvl == 0) ? 100 : (lvl == 1) ? 50 : (lvl == 2) ? 25 : 13;
    const float fw = (float)wi;
    const int sti = (lvl == 0) ? 0 : (lvl == 1) ? 10000 : (lvl == 2) ? 12500 : 13125;
    const float rw = (lvl == 0) ? 0.01f : (lvl == 1) ? 0.02f
                   : (lvl == 2) ? 0.04f : (1.0f / 13.0f);
    const float2 rp = *(const float2*)(refp + (size_t)bq * 8 + lvl * 2);
    const float4 o4 = *(const float4*)(rowp + h * 32 + lc * 4);

    int   rA0, rB0, cA0, cB0, rA1, rB1, cA1, cB1;
    float wxA0, wxB0, wyA0, wyB0, wxA1, wxB1, wyA1, wyB1;

    auto prep = [&](float ox, float oy, float ek,
                    int& rA, int& rB, int& cA, int& cB,
                    float& wxA, float& wxB, float& wyA, float& wyB) {
        const float x = fmaf(fmaf(ox, rw, rp.x), fw, -0.5f);
        const float y = fmaf(fmaf(oy, rw, rp.y), fw, -0.5f);
        const float x0f = floorf(x), y0f = floorf(y);
        const int ix = (int)x0f, iy = (int)y0f;
        const float wx1 = x - x0f, wy1 = y - y0f;
        wxA = ((unsigned)ix        < (unsigned)wi) ? 1.f - wx1 : 0.f;
        wxB = ((unsigned)(ix + 1)  < (unsigned)wi) ? wx1       : 0.f;
        wyA = (((unsigned)iy       < (unsigned)wi) ? 1.f - wy1 : 0.f) * ek;
        wyB = (((unsigned)(iy + 1) < (unsigned)wi) ? wy1       : 0.f) * ek;
        const int xc0 = min(max(ix, 0),     wi - 1);
        const int xc1 = min(max(ix + 1, 0), wi - 1);
        const int yc0 = min(max(iy, 0),     wi - 1);
        const int yc1 = min(max(iy + 1, 0), wi - 1);
        rA = sti + yc0 * wi; rB = sti + yc1 * wi;
        cA = xc0;            cB = xc1;
    };
    prep(o4.x, o4.y, e0, rA0, rB0, cA0, cB0, wxA0, wxB0, wyA0, wyB0);
    prep(o4.z, o4.w, e1, rA1, rB1, cA1, cB1, wxA1, wxB1, wyA1, wyB1);

    // uniform base for head-plane, per-lane 32-bit byte offset (b, lc folded)
    const char* hplane = (const char*)(value + (size_t)h * SN * DH);
    const unsigned lnoff = (unsigned)b * (NH * SN * DH * 2) + lc * 8;

    float ax = 0.f, ay = 0.f, az = 0.f, aw_ = 0.f;

    #pragma unroll
    for (int p = 0; p < 16; ++p) {
        const int src = gbase + (p >> 1);
        const int   rA  = __shfl((p & 1) ? rA1  : rA0,  src, 64);
        const int   rB  = __shfl((p & 1) ? rB1  : rB0,  src, 64);
        const int   cA  = __shfl((p & 1) ? cA1  : cA0,  src, 64);
        const int   cB  = __shfl((p & 1) ? cB1  : cB0,  src, 64);
        const float wxA = __shfl((p & 1) ? wxA1 : wxA0, src, 64);
        const float wxB = __shfl((p & 1) ? wxB1 : wxB0, src, 64);
        const float wyA = __shfl((p & 1) ? wyA1 : wyA0, src, 64);
        const float wyB = __shfl((p & 1) ? wyB1 : wyB0, src, 64);

        #pragma unroll
        for (int c = 0; c < 4; ++c) {
            const int cell  = ((c >> 1) ? rB : rA) + ((c & 1) ? cB : cA);
            const float cw  = ((c & 1) ? wxB : wxA) * ((c >> 1) ? wyB : wyA);
            const uint2 v = *(const uint2*)(hplane + ((unsigned)cell * 64u + lnoff));
            ax  = fmaf(cw, asf(v.x << 16),          ax);
            ay  = fmaf(cw, asf(v.x & 0xffff0000u),  ay);
            az  = fmaf(cw, asf(v.y << 16),          az);
            aw_ = fmaf(cw, asf(v.y & 0xffff0000u),  aw_);
        }
    }

    ushort4 o;
    o.x = f2bf(ax); o.y = f2bf(ay); o.z = f2bf(az); o.w = f2bf(aw_);
    *(ushort4*)(outh + (size_t)bq * 256 + h * 32 + lc * 4) = o;
}

// ---------------------------------------------------------------------------
// Workspace (~68.5 MB, NO aliasing; each region: one producer, later readers):
//   valueb [MQ*256 bf16]  <- gemm value (MODE1, fp32 A=enc)  -> ms_sample
//   offaw  [MQ*384 f32 ]  <- merged off+attn gemm (fp32 A=hs)-> ms_sample
//   outh   [MQ*256 bf16]  <- ms_sample                        -> gemm out
//   WvT/WcatT/WoutT       <- conv_weights                     -> gemms
// ---------------------------------------------------------------------------
extern "C" void kernel_launch(void* const* d_in, const int* in_sizes, int n_in,
                              void* d_out, int out_size, void* d_ws, size_t ws_size,
                              hipStream_t stream) {
    const float* hs   = (const float*)d_in[0];
    const float* enc  = (const float*)d_in[1];
    const float* refp = (const float*)d_in[2];
    const float* Wv   = (const float*)d_in[3];
    const float* bv   = (const float*)d_in[4];
    const float* Woff = (const float*)d_in[5];
    const float* boff = (const float*)d_in[6];
    const float* Wa   = (const float*)d_in[7];
    const float* ba   = (const float*)d_in[8];
    const float* Wout = (const float*)d_in[9];
    const float* bout = (const float*)d_in[10];

    float* out    = (float*)d_out;
    float* aw_out = out + (size_t)BQn * QN * 256;

    const size_t MQ = (size_t)BQn * QN;      // 26588
    unsigned short* valueb = (unsigned short*)d_ws;              // MQ*256 bf16
    float* offaw = (float*)(valueb + MQ * 256);                  // MQ*384 f32
    unsigned short* outh  = (unsigned short*)(offaw + MQ * 384); // MQ*256 bf16
    unsigned short* WvT   = outh + MQ * 256;                     // 256*256
    unsigned short* WcatT = WvT + 256 * 256;                     // 384*256
    unsigned short* WoutT = WcatT + 384 * 256;                   // 256*256

    const int M = (int)MQ;
    const dim3 blk(256);

    conv_weights<<<896, blk, 0, stream>>>(Wv, Woff, Wa, Wout,
                                          WvT, WcatT, WcatT + 65536, WoutT);

    const int my = (M + 63) / 64;             // 416
    gemm_mfma<256, 1, true ><<<dim3(2, my), blk, 0, stream>>>(
        enc, WvT, bv, bv, valueb, M);
    gemm_mfma<384, 0, true ><<<dim3(3, my), blk, 0, stream>>>(
        hs, WcatT, boff, ba, offaw, M);

    const int qchunks = (M + 31) / 32;        // 831
    ms_sample<<<8 * qchunks, blk, 0, stream>>>(valueb, offaw, refp,
                                               outh, aw_out);

    gemm_mfma<256, 0, false><<<dim3(2, my), blk, 0, stream>>>(
        outh, WoutT, bout, bout, out, M);
}

// Round 13
// 128.733 us; speedup vs baseline: 1.4122x; 1.4122x over previous
//
#include <hip/hip_runtime.h>
#include <hip/hip_bf16.h>
#include <math.h>

#define BQn 2
#define QN 13294
#define SN 13294
#define NH 8
#define DH 32
#define DM 256

typedef __attribute__((ext_vector_type(8))) short short8;
typedef __attribute__((ext_vector_type(4))) float f32x4;

__device__ __forceinline__ unsigned short f2bf(float x) {
    union { float f; unsigned int u; } c; c.f = x;
    unsigned int r = c.u + 0x7fff + ((c.u >> 16) & 1);   // RNE
    return (unsigned short)(r >> 16);
}
__device__ __forceinline__ float asf(unsigned int u) {
    union { unsigned int i; float f; } c; c.i = u; return c.f;
}

// ---------------------------------------------------------------------------
// Fused transpose+bf16 of all four weight matrices: W[K][N] -> WT[N][K]
// WoffT/WaT adjacent -> WcatT[384][256] for the merged off+attn GEMM.
// ---------------------------------------------------------------------------
__global__ __launch_bounds__(256) void conv_weights(
    const float* __restrict__ Wv, const float* __restrict__ Woff,
    const float* __restrict__ Wa, const float* __restrict__ Wout,
    unsigned short* __restrict__ WvT, unsigned short* __restrict__ WoffT,
    unsigned short* __restrict__ WaT, unsigned short* __restrict__ WoutT)
{
    const int t = blockIdx.x * 256 + threadIdx.x;
    if (t < 65536) {
        const int n = t & 255, k = t >> 8;
        WvT[(size_t)n * 256 + k] = f2bf(Wv[(size_t)k * 256 + n]);
    } else if (t < 131072) {
        const int i = t - 65536, n = i & 255, k = i >> 8;
        WoffT[(size_t)n * 256 + k] = f2bf(Woff[(size_t)k * 256 + n]);
    } else if (t < 163840) {
        const int i = t - 131072, n = i & 127, k = i >> 7;
        WaT[(size_t)n * 256 + k] = f2bf(Wa[(size_t)k * 128 + n]);
    } else if (t < 229376) {
        const int i = t - 163840, n = i & 255, k = i >> 8;
        WoutT[(size_t)n * 256 + k] = f2bf(Wout[(size_t)k * 256 + n]);
    }
}

// ---------------------------------------------------------------------------
// Merged value+offaw GEMM (round-11 proven 64x128 tile, BK=64, 4 waves):
//   blockIdx.x < 2 : valueb = enc @ WvT^T + bv   (bf16 value layout)
//   blockIdx.x >= 2: offaw  = hs @ WcatT^T + b   (f32 row-major, N=384)
// 2080 blocks at 5 blocks/CU (LDS 27.6 KB) = 1.6 fill rounds; tails overlap.
// A fp32 -> bf16 in staging (v_cvt_pk_bf16_f32).
// ---------------------------------------------------------------------------
__global__ __launch_bounds__(256) void gemm_dual(
    const float* __restrict__ A0, const float* __restrict__ A1,
    const unsigned short* __restrict__ WT0,
    const unsigned short* __restrict__ WT1,
    const float* __restrict__ bv, const float* __restrict__ boff,
    const float* __restrict__ ba,
    unsigned short* __restrict__ C0, float* __restrict__ C1, int M)
{
    __shared__ unsigned short As[64][72];   // +8 pad: 2-way alias only (free)
    __shared__ unsigned short Bs[128][72];
    const int tid  = threadIdx.x;
    const int lane = tid & 63, wid = tid >> 6;
    const int wr = wid >> 1, wc = wid & 1;
    const bool second = (blockIdx.x >= 2);
    const float* A = second ? A1 : A0;
    const unsigned short* WT = second ? WT1 : WT0;
    const int n0 = (second ? (int)blockIdx.x - 2 : (int)blockIdx.x) * 128;
    const int r0 = blockIdx.y * 64;

    f32x4 acc[2][4] = {};

    for (int k0 = 0; k0 < 256; k0 += 64) {
        #pragma unroll
        for (int i = 0; i < 2; ++i) {           // A tile 64x64 (fp32 -> bf16)
            const int idx = i * 256 + tid;
            const int row = idx >> 3, ch = (idx & 7) << 3;
            int grow = r0 + row; if (grow >= M) grow = M - 1;
            const float4 v0 = *(const float4*)(A + (size_t)grow * 256 + k0 + ch);
            const float4 v1 = *(const float4*)(A + (size_t)grow * 256 + k0 + ch + 4);
            union { __hip_bfloat162 b[4]; uint4 u; } pk;
            pk.b[0] = __float22bfloat162_rn(make_float2(v0.x, v0.y));
            pk.b[1] = __float22bfloat162_rn(make_float2(v0.z, v0.w));
            pk.b[2] = __float22bfloat162_rn(make_float2(v1.x, v1.y));
            pk.b[3] = __float22bfloat162_rn(make_float2(v1.z, v1.w));
            *(uint4*)&As[row][ch] = pk.u;
        }
        #pragma unroll
        for (int i = 0; i < 4; ++i) {           // B tile 128x64 (rows = N cols)
            const int idx = i * 256 + tid;
            const int row = idx >> 3, ch = (idx & 7) << 3;
            *(uint4*)&Bs[row][ch] =
                *(const uint4*)(WT + (size_t)(n0 + row) * 256 + k0 + ch);
        }
        __syncthreads();
        #pragma unroll
        for (int kk = 0; kk < 2; ++kk) {
            const int kb = kk * 32 + (lane >> 4) * 8;
            short8 bfr[4];
            #pragma unroll
            for (int n = 0; n < 4; ++n)
                bfr[n] = *(const short8*)&Bs[wc * 64 + n * 16 + (lane & 15)][kb];
            #pragma unroll
            for (int m = 0; m < 2; ++m) {
                const short8 afr =
                    *(const short8*)&As[wr * 32 + m * 16 + (lane & 15)][kb];
                #pragma unroll
                for (int n = 0; n < 4; ++n)
                    acc[m][n] = __builtin_amdgcn_mfma_f32_16x16x32_bf16(
                        afr, bfr[n], acc[m][n], 0, 0, 0);
            }
        }
        __syncthreads();
    }

    #pragma unroll
    for (int m = 0; m < 2; ++m)
        #pragma unroll
        for (int n = 0; n < 4; ++n) {
            const int col = n0 + wc * 64 + n * 16 + (lane & 15);
            const float bsv = second
                ? ((col < 256) ? boff[col] : ba[col - 256])
                : bv[col];
            #pragma unroll
            for (int j = 0; j < 4; ++j) {
                const int row = r0 + wr * 32 + m * 16 + (lane >> 4) * 4 + j;
                if (row >= M) continue;
                const float v = acc[m][n][j] + bsv;
                if (second) {
                    C1[(size_t)row * 384 + col] = v;
                } else {
                    const int b = (row >= SN), s = row - b * SN;
                    const int h = col >> 5, dh = col & 31;
                    C0[(((size_t)b * NH + h) * SN + s) * DH + dh] = f2bf(v);
                }
            }
        }
}

// ---------------------------------------------------------------------------
// Out-projection GEMM (bf16 A): C[M,256] = A @ WT^T + bias, 64x128 tile
// (round-11 proven structure).
// ---------------------------------------------------------------------------
__global__ __launch_bounds__(256) void gemm_out(
    const unsigned short* __restrict__ A,   // [M][256] bf16
    const unsigned short* __restrict__ WT,  // [256][256] bf16
    const float* __restrict__ bias,
    float* __restrict__ C, int M)
{
    __shared__ unsigned short As[64][72];
    __shared__ unsigned short Bs[128][72];
    const int tid  = threadIdx.x;
    const int lane = tid & 63, wid = tid >> 6;
    const int wr = wid >> 1, wc = wid & 1;
    const int r0 = blockIdx.y * 64, n0 = blockIdx.x * 128;

    f32x4 acc[2][4] = {};

    for (int k0 = 0; k0 < 256; k0 += 64) {
        #pragma unroll
        for (int i = 0; i < 2; ++i) {
            const int idx = i * 256 + tid;
            const int row = idx >> 3, ch = (idx & 7) << 3;
            int grow = r0 + row; if (grow >= M) grow = M - 1;
            *(uint4*)&As[row][ch] =
                *(const uint4*)(A + (size_t)grow * 256 + k0 + ch);
        }
        #pragma unroll
        for (int i = 0; i < 4; ++i) {
            const int idx = i * 256 + tid;
            const int row = idx >> 3, ch = (idx & 7) << 3;
            *(uint4*)&Bs[row][ch] =
                *(const uint4*)(WT + (size_t)(n0 + row) * 256 + k0 + ch);
        }
        __syncthreads();
        #pragma unroll
        for (int kk = 0; kk < 2; ++kk) {
            const int kb = kk * 32 + (lane >> 4) * 8;
            short8 bfr[4];
            #pragma unroll
            for (int n = 0; n < 4; ++n)
                bfr[n] = *(const short8*)&Bs[wc * 64 + n * 16 + (lane & 15)][kb];
            #pragma unroll
            for (int m = 0; m < 2; ++m) {
                const short8 afr =
                    *(const short8*)&As[wr * 32 + m * 16 + (lane & 15)][kb];
                #pragma unroll
                for (int n = 0; n < 4; ++n)
                    acc[m][n] = __builtin_amdgcn_mfma_f32_16x16x32_bf16(
                        afr, bfr[n], acc[m][n], 0, 0, 0);
            }
        }
        __syncthreads();
    }

    #pragma unroll
    for (int m = 0; m < 2; ++m)
        #pragma unroll
        for (int n = 0; n < 4; ++n) {
            const int col = n0 + wc * 64 + n * 16 + (lane & 15);
            const float bsv = bias[col];
            #pragma unroll
            for (int j = 0; j < 4; ++j) {
                const int row = r0 + wr * 32 + m * 16 + (lane >> 4) * 4 + j;
                if (row >= M) continue;
                C[(size_t)row * 256 + col] = acc[m][n][j] + bsv;
            }
        }
}

// ---------------------------------------------------------------------------
// Deformable sampling v5 (owner-compute; proven: 67 us, VGPR 36):
// block = (head, 32-query chunk); h = blockIdx.x & 7 pins each head's two
// bf16 value planes in one XCD's L2. 8 lanes per (b,q,h); lane lc owns
// channels [4lc,4lc+4) AND point-pairs 2lc,2lc+1. Owner precomputes clamped
// rows/cols + validity-and-attention-folded bilinear weights; group
// shfl-broadcasts 8 results per point.
// ---------------------------------------------------------------------------
__global__ __launch_bounds__(256) void ms_sample(
    const unsigned short* __restrict__ value, // [B,H,S,32] bf16
    const float* __restrict__ offaw,          // [B*Q,384] (256 off | 128 logits)
    const float* __restrict__ refp,           // [B,Q,4,2]
    unsigned short* __restrict__ outh,        // [B,Q,256] bf16
    float* __restrict__ awout)                // [B,Q,128]
{
    const int h  = blockIdx.x & 7;
    const int qc = blockIdx.x >> 3;
    const int lc = threadIdx.x & 7;
    const int bq = qc * 32 + (threadIdx.x >> 3);
    if (bq >= BQn * QN) return;
    const int b  = (bq >= QN);
    const int gbase = threadIdx.x & 56;

    const float* rowp = offaw + (size_t)bq * 384;

    // distributed softmax over 16 logits: 2 per lane
    const float2 lw2 = *(const float2*)(rowp + 256 + h * 16 + lc * 2);
    float m = fmaxf(lw2.x, lw2.y);
    #pragma unroll
    for (int d = 1; d < 8; d <<= 1) m = fmaxf(m, __shfl_xor(m, d, 8));
    float e0 = __expf(lw2.x - m), e1 = __expf(lw2.y - m);
    float s = e0 + e1;
    #pragma unroll
    for (int d = 1; d < 8; d <<= 1) s += __shfl_xor(s, d, 8);
    const float inv = 1.f / s;
    e0 *= inv; e1 *= inv;
    *(float2*)(awout + (size_t)bq * 128 + h * 16 + lc * 2) = make_float2(e0, e1);

    // ---- owner precompute: this lane's level constants + its two points ----
    const int lvl = lc >> 1;
    const int wi  = (lvl == 0) ? 100 : (lvl == 1) ? 50 : (lvl == 2) ? 25 : 13;
    const float fw = (float)wi;
    const int sti = (lvl == 0) ? 0 : (lvl == 1) ? 10000 : (lvl == 2) ? 12500 : 13125;
    const float rw = (lvl == 0) ? 0.01f : (lvl == 1) ? 0.02f
                   : (lvl == 2) ? 0.04f : (1.0f / 13.0f);
    const float2 rp = *(const float2*)(refp + (size_t)bq * 8 + lvl * 2);
    const float4 o4 = *(const float4*)(rowp + h * 32 + lc * 4);

    int   rA0, rB0, cA0, cB0, rA1, rB1, cA1, cB1;
    float wxA0, wxB0, wyA0, wyB0, wxA1, wxB1, wyA1, wyB1;

    auto prep = [&](float ox, float oy, float ek,
                    int& rA, int& rB, int& cA, int& cB,
                    float& wxA, float& wxB, float& wyA, float& wyB) {
        const float x = fmaf(fmaf(ox, rw, rp.x), fw, -0.5f);
        const float y = fmaf(fmaf(oy, rw, rp.y), fw, -0.5f);
        const float x0f = floorf(x), y0f = floorf(y);
        const int ix = (int)x0f, iy = (int)y0f;
        const float wx1 = x - x0f, wy1 = y - y0f;
        wxA = ((unsigned)ix        < (unsigned)wi) ? 1.f - wx1 : 0.f;
        wxB = ((unsigned)(ix + 1)  < (unsigned)wi) ? wx1       : 0.f;
        wyA = (((unsigned)iy       < (unsigned)wi) ? 1.f - wy1 : 0.f) * ek;
        wyB = (((unsigned)(iy + 1) < (unsigned)wi) ? wy1       : 0.f) * ek;
        const int xc0 = min(max(ix, 0),     wi - 1);
        const int xc1 = min(max(ix + 1, 0), wi - 1);
        const int yc0 = min(max(iy, 0),     wi - 1);
        const int yc1 = min(max(iy + 1, 0), wi - 1);
        rA = sti + yc0 * wi; rB = sti + yc1 * wi;
        cA = xc0;            cB = xc1;
    };
    prep(o4.x, o4.y, e0, rA0, rB0, cA0, cB0, wxA0, wxB0, wyA0, wyB0);
    prep(o4.z, o4.w, e1, rA1, rB1, cA1, cB1, wxA1, wxB1, wyA1, wyB1);

    // uniform base for head-plane, per-lane 32-bit byte offset (b, lc folded)
    const char* hplane = (const char*)(value + (size_t)h * SN * DH);
    const unsigned lnoff = (unsigned)b * (NH * SN * DH * 2) + lc * 8;

    float ax = 0.f, ay = 0.f, az = 0.f, aw_ = 0.f;

    #pragma unroll
    for (int p = 0; p < 16; ++p) {
        const int src = gbase + (p >> 1);
        const int   rA  = __shfl((p & 1) ? rA1  : rA0,  src, 64);
        const int   rB  = __shfl((p & 1) ? rB1  : rB0,  src, 64);
        const int   cA  = __shfl((p & 1) ? cA1  : cA0,  src, 64);
        const int   cB  = __shfl((p & 1) ? cB1  : cB0,  src, 64);
        const float wxA = __shfl((p & 1) ? wxA1 : wxA0, src, 64);
        const float wxB = __shfl((p & 1) ? wxB1 : wxB0, src, 64);
        const float wyA = __shfl((p & 1) ? wyA1 : wyA0, src, 64);
        const float wyB = __shfl((p & 1) ? wyB1 : wyB0, src, 64);

        #pragma unroll
        for (int c = 0; c < 4; ++c) {
            const int cell  = ((c >> 1) ? rB : rA) + ((c & 1) ? cB : cA);
            const float cw  = ((c & 1) ? wxB : wxA) * ((c >> 1) ? wyB : wyA);
            const uint2 v = *(const uint2*)(hplane + ((unsigned)cell * 64u + lnoff));
            ax  = fmaf(cw, asf(v.x << 16),          ax);
            ay  = fmaf(cw, asf(v.x & 0xffff0000u),  ay);
            az  = fmaf(cw, asf(v.y << 16),          az);
            aw_ = fmaf(cw, asf(v.y & 0xffff0000u),  aw_);
        }
    }

    ushort4 o;
    o.x = f2bf(ax); o.y = f2bf(ay); o.z = f2bf(az); o.w = f2bf(aw_);
    *(ushort4*)(outh + (size_t)bq * 256 + h * 32 + lc * 4) = o;
}

// ---------------------------------------------------------------------------
// Workspace (~68.5 MB, NO aliasing; each region: one producer, later readers):
//   valueb [MQ*256 bf16]  <- gemm_dual (x<2)   -> ms_sample
//   offaw  [MQ*384 f32 ]  <- gemm_dual (x>=2)  -> ms_sample
//   outh   [MQ*256 bf16]  <- ms_sample         -> gemm_out
//   WvT/WcatT/WoutT       <- conv_weights      -> gemms
// ---------------------------------------------------------------------------
extern "C" void kernel_launch(void* const* d_in, const int* in_sizes, int n_in,
                              void* d_out, int out_size, void* d_ws, size_t ws_size,
                              hipStream_t stream) {
    const float* hs   = (const float*)d_in[0];
    const float* enc  = (const float*)d_in[1];
    const float* refp = (const float*)d_in[2];
    const float* Wv   = (const float*)d_in[3];
    const float* bv   = (const float*)d_in[4];
    const float* Woff = (const float*)d_in[5];
    const float* boff = (const float*)d_in[6];
    const float* Wa   = (const float*)d_in[7];
    const float* ba   = (const float*)d_in[8];
    const float* Wout = (const float*)d_in[9];
    const float* bout = (const float*)d_in[10];

    float* out    = (float*)d_out;
    float* aw_out = out + (size_t)BQn * QN * 256;

    const size_t MQ = (size_t)BQn * QN;      // 26588
    unsigned short* valueb = (unsigned short*)d_ws;              // MQ*256 bf16
    float* offaw = (float*)(valueb + MQ * 256);                  // MQ*384 f32
    unsigned short* outh  = (unsigned short*)(offaw + MQ * 384); // MQ*256 bf16
    unsigned short* WvT   = outh + MQ * 256;                     // 256*256
    unsigned short* WcatT = WvT + 256 * 256;                     // 384*256
    unsigned short* WoutT = WcatT + 384 * 256;                   // 256*256

    const int M = (int)MQ;
    const dim3 blk(256);

    conv_weights<<<896, blk, 0, stream>>>(Wv, Woff, Wa, Wout,
                                          WvT, WcatT, WcatT + 65536, WoutT);

    const int my = (M + 63) / 64;             // 416
    gemm_dual<<<dim3(5, my), blk, 0, stream>>>(
        enc, hs, WvT, WcatT, bv, boff, ba, valueb, offaw, M);

    const int qchunks = (M + 31) / 32;        // 831
    ms_sample<<<8 * qchunks, blk, 0, stream>>>(valueb, offaw, refp,
                                               outh, aw_out);

    gemm_out<<<dim3(2, my), blk, 0, stream>>>(outh, WoutT, bout, out, M);
}